// Round 10
// baseline (170.505 us; speedup 1.0000x reference)
//
#include <hip/hip_runtime.h>

typedef __attribute__((ext_vector_type(8))) short bf16x8;
typedef __attribute__((ext_vector_type(4))) short bf16x4;
typedef __attribute__((ext_vector_type(4))) float f32x4;

#define NB 128
#define LL 512
#define HH 128
#define HDIM 64
#define NROWS (NB * LL)  // 65536

#define SB __builtin_amdgcn_sched_barrier(0)

__device__ __forceinline__ unsigned short f2b(float f) {
  unsigned int x = __float_as_uint(f);
  x = (x + 0x7fffu + ((x >> 16) & 1u)) >> 16;  // RNE
  return (unsigned short)x;
}

__device__ __forceinline__ bf16x8 load8_cvt(const float* p) {
  float4 a = *(const float4*)p;
  float4 b = *(const float4*)(p + 4);
  bf16x8 r;
  r[0] = (short)f2b(a.x); r[1] = (short)f2b(a.y);
  r[2] = (short)f2b(a.z); r[3] = (short)f2b(a.w);
  r[4] = (short)f2b(b.x); r[5] = (short)f2b(b.y);
  r[6] = (short)f2b(b.z); r[7] = (short)f2b(b.w);
  return r;
}

#if __has_builtin(__builtin_amdgcn_mfma_f32_16x16x16bf16_1k)
__device__ __forceinline__ f32x4 mfma16(bf16x4 a, bf16x4 b, f32x4 c) {
  return __builtin_amdgcn_mfma_f32_16x16x16bf16_1k(a, b, c, 0, 0, 0);
}
#else
__device__ __forceinline__ f32x4 mfma16(bf16x4 a, bf16x4 b, f32x4 c) {
  asm volatile("s_nop 1\n\t"
               "v_mfma_f32_16x16x16_bf16 %0, %1, %2, %0\n\t"
               "s_nop 7\n\t"
               "s_nop 7"
               : "+v"(c) : "v"(a), "v"(b));
  return c;
}
#endif

__device__ __forceinline__ f32x4 mfma32(bf16x8 a, bf16x8 b, f32x4 c) {
  return __builtin_amdgcn_mfma_f32_16x16x32_bf16(a, b, c, 0, 0, 0);
}

// ---------------------------------------------------------------------------
// Weight pre-convert: fp32 -> bf16, LINEAR layout Wb[3][128][128] (Q,K,V).
// ---------------------------------------------------------------------------
__global__ __launch_bounds__(256) void wcvt_kernel(
    const float* __restrict__ Qw, const float* __restrict__ Kw,
    const float* __restrict__ Vw, unsigned short* __restrict__ Wb) {
  const int i = blockIdx.x * 256 + threadIdx.x;  // 0..12287 float4s
  const float* src = (i < 4096) ? Qw : (i < 8192) ? Kw : Vw;
  const int off = (i & 4095) << 2;
  float4 v = *(const float4*)(src + off);
  ushort4 u;
  u.x = f2b(v.x); u.y = f2b(v.y); u.z = f2b(v.z); u.w = f2b(v.w);
  *(ushort4*)(Wb + ((size_t)i << 2)) = u;
}

// ---------------------------------------------------------------------------
// KV projection (R7 version): Kw+Vw in 64KB LDS, SB-pinned pipeline.
// ---------------------------------------------------------------------------
__global__ __launch_bounds__(512, 4) void kv_proj_kernel(
    const float* __restrict__ keys, const float* __restrict__ nbr,
    const float* __restrict__ nat, const float* __restrict__ pk,
    const float* __restrict__ pv, const unsigned short* __restrict__ Wb,
    const float* __restrict__ Kbias, const float* __restrict__ Vbias,
    unsigned short* __restrict__ Ko, unsigned short* __restrict__ Vt) {
  __shared__ unsigned short wlds[2 * 128 * 128];  // 64 KB: Kw, Vw (swizzled)

  const int tid = threadIdx.x;
  const int lane = tid & 63;
  const int wave = tid >> 6;
  const int g = lane >> 4;
  const int qi = lane & 15;

#pragma unroll
  for (int i = 0; i < 8; ++i) {
    const int byte = (tid + i * 512) * 16;
    const int row = (byte >> 8) & 127;
    *(bf16x8*)((char*)wlds + (byte ^ ((row & 7) << 4))) =
        *(const bf16x8*)((const char*)Wb + 32768 + byte);
  }

  const long row = (long)blockIdx.x * 128 + wave * 16 + qi;
  const int rswz = (qi & 7) << 4;
  const long roff = row * 128;

  float4 Anb[8], Ana[8], Apk[8], Apv[8];
  float4 tmp[8];
  f32x4 accK[8], accV[8];

  float4 xr[8];
#pragma unroll
  for (int j = 0; j < 8; ++j)
    xr[j] = *(const float4*)(keys + roff + (j >> 1) * 32 + g * 8 + (j & 1) * 4);
#pragma unroll
  for (int ct = 0; ct < 2; ++ct) {
    const int c0 = ct * 16 + 4 * g;
    Anb[ct] = *(const float4*)(nbr + roff + c0);
    Ana[ct] = *(const float4*)(nat + roff + c0);
    Apk[ct] = *(const float4*)(pk + roff + c0);
  }
  SB;
  bf16x8 xk[4];
#pragma unroll
  for (int kt = 0; kt < 4; ++kt) {
    const float4 a = xr[2 * kt], b = xr[2 * kt + 1];
    bf16x8 r;
    r[0] = (short)f2b(a.x); r[1] = (short)f2b(a.y);
    r[2] = (short)f2b(a.z); r[3] = (short)f2b(a.w);
    r[4] = (short)f2b(b.x); r[5] = (short)f2b(b.y);
    r[6] = (short)f2b(b.z); r[7] = (short)f2b(b.w);
    xk[kt] = r;
  }
  __syncthreads();

#pragma unroll
  for (int ct = 2; ct < 6; ++ct) {
    const int c0 = ct * 16 + 4 * g;
    Anb[ct] = *(const float4*)(nbr + roff + c0);
    Ana[ct] = *(const float4*)(nat + roff + c0);
    Apk[ct] = *(const float4*)(pk + roff + c0);
  }
  SB;

#define MFMA_K_PAIR(c)                                                      \
  {                                                                         \
    _Pragma("unroll") for (int ct = (c); ct < (c) + 2; ++ct) {              \
      accK[ct] = f32x4{0.f, 0.f, 0.f, 0.f};                                 \
      _Pragma("unroll") for (int kt = 0; kt < 4; ++kt) {                    \
        const int byte = (ct * 16 + qi) * 256 + ((kt * 64 + g * 16) ^ rswz);\
        bf16x8 wf = *(const bf16x8*)((const char*)wlds + byte);             \
        accK[ct] = mfma32(wf, xk[kt], accK[ct]);                            \
      }                                                                     \
    }                                                                       \
  }

#define MFMA_V_PAIR(c)                                                      \
  {                                                                         \
    _Pragma("unroll") for (int ct = (c); ct < (c) + 2; ++ct) {              \
      accV[ct] = f32x4{0.f, 0.f, 0.f, 0.f};                                 \
      _Pragma("unroll") for (int kt = 0; kt < 4; ++kt) {                    \
        const int byte =                                                    \
            32768 + (ct * 16 + qi) * 256 + ((kt * 64 + g * 16) ^ rswz);     \
        bf16x8 wf = *(const bf16x8*)((const char*)wlds + byte);             \
        accV[ct] = mfma32(wf, xk[kt], accV[ct]);                            \
      }                                                                     \
    }                                                                       \
  }

#define EPI_K_PAIR(c)                                                       \
  {                                                                         \
    _Pragma("unroll") for (int ct = (c); ct < (c) + 2; ++ct) {              \
      const int c0 = ct * 16 + 4 * g;                                       \
      const float4 bv = *(const float4*)(Kbias + c0);                       \
      float4 t;                                                             \
      t.x = Anb[ct].x + Ana[ct].x; t.y = Anb[ct].y + Ana[ct].y;             \
      t.z = Anb[ct].z + Ana[ct].z; t.w = Anb[ct].w + Ana[ct].w;             \
      tmp[ct] = t;                                                          \
      ushort4 u;                                                            \
      u.x = f2b(accK[ct][0] + bv.x + t.x + Apk[ct].x);                      \
      u.y = f2b(accK[ct][1] + bv.y + t.y + Apk[ct].y);                      \
      u.z = f2b(accK[ct][2] + bv.z + t.z + Apk[ct].z);                      \
      u.w = f2b(accK[ct][3] + bv.w + t.w + Apk[ct].w);                      \
      *(ushort4*)(Ko + roff + c0) = u;                                      \
    }                                                                       \
  }

#define EPI_V_PAIR(c)                                                       \
  {                                                                         \
    _Pragma("unroll") for (int ct = (c); ct < (c) + 2; ++ct) {              \
      const int c0 = ct * 16 + 4 * g;                                       \
      const float4 bv = *(const float4*)(Vbias + c0);                       \
      const int hh = c0 >> 6, d0 = c0 & 63;                                 \
      unsigned short* vp =                                                  \
          Vt + (((long)hh * NB + bidx) * HDIM + d0) * LL + lrow;            \
      vp[0 * LL] = f2b(accV[ct][0] + bv.x + tmp[ct].x + Apv[ct].x);         \
      vp[1 * LL] = f2b(accV[ct][1] + bv.y + tmp[ct].y + Apv[ct].y);         \
      vp[2 * LL] = f2b(accV[ct][2] + bv.z + tmp[ct].z + Apv[ct].z);         \
      vp[3 * LL] = f2b(accV[ct][3] + bv.w + tmp[ct].w + Apv[ct].w);         \
    }                                                                       \
  }

#define ISSUE_A_PAIR(c)                                                     \
  {                                                                         \
    _Pragma("unroll") for (int ct = (c); ct < (c) + 2; ++ct) {              \
      const int c0 = ct * 16 + 4 * g;                                       \
      Anb[ct] = *(const float4*)(nbr + roff + c0);                          \
      Ana[ct] = *(const float4*)(nat + roff + c0);                          \
      Apk[ct] = *(const float4*)(pk + roff + c0);                           \
    }                                                                       \
  }

#define ISSUE_PV_PAIR(c)                                                    \
  {                                                                         \
    _Pragma("unroll") for (int ct = (c); ct < (c) + 2; ++ct) {              \
      Apv[ct] = *(const float4*)(pv + roff + ct * 16 + 4 * g);              \
    }                                                                       \
  }

  const long bidx = row >> 9, lrow = row & 511;

  MFMA_K_PAIR(0); SB;
  EPI_K_PAIR(0); SB;
  ISSUE_A_PAIR(6); SB;
  MFMA_K_PAIR(2); SB;
  EPI_K_PAIR(2); SB;
  ISSUE_PV_PAIR(0); SB;
  MFMA_K_PAIR(4); SB;
  EPI_K_PAIR(4); SB;
  ISSUE_PV_PAIR(2); SB;
  MFMA_K_PAIR(6); SB;
  EPI_K_PAIR(6); SB;
  ISSUE_PV_PAIR(4); SB;
  MFMA_V_PAIR(0); SB;
  EPI_V_PAIR(0); SB;
  ISSUE_PV_PAIR(6); SB;
  MFMA_V_PAIR(2); SB;
  EPI_V_PAIR(2); SB;
  MFMA_V_PAIR(4); SB;
  EPI_V_PAIR(4); SB;
  MFMA_V_PAIR(6); SB;
  EPI_V_PAIR(6);
}

// ---------------------------------------------------------------------------
// Q projection (R7 version): Qw in 32KB LDS.
// ---------------------------------------------------------------------------
__global__ __launch_bounds__(512) void q_proj_kernel(
    const float* __restrict__ queries, const unsigned short* __restrict__ Wb,
    const float* __restrict__ Qbias, unsigned short* __restrict__ Qo) {
  __shared__ unsigned short wlds[128 * 128];  // 32 KB

  const int tid = threadIdx.x;
  const int lane = tid & 63;
  const int wave = tid >> 6;
  const int g = lane >> 4, qi = lane & 15;

#pragma unroll
  for (int i = 0; i < 4; ++i) {
    const int byte = (tid + i * 512) * 16;
    const int row = (byte >> 8) & 127;
    *(bf16x8*)((char*)wlds + (byte ^ ((row & 7) << 4))) =
        *(const bf16x8*)((const char*)Wb + byte);
  }

  const long row = (long)blockIdx.x * 128 + wave * 16 + qi;
  const int rswz = (qi & 7) << 4;
  const long roff = row * 128;

  bf16x8 xq[4];
#pragma unroll
  for (int kt = 0; kt < 4; ++kt)
    xq[kt] = load8_cvt(queries + roff + kt * 32 + g * 8);

  __syncthreads();

  f32x4 acc[8];
#pragma unroll
  for (int ct = 0; ct < 8; ++ct) {
    acc[ct] = f32x4{0.f, 0.f, 0.f, 0.f};
#pragma unroll
    for (int kt = 0; kt < 4; ++kt) {
      const int byte = (ct * 16 + qi) * 256 + ((kt * 64 + g * 16) ^ rswz);
      bf16x8 wf = *(const bf16x8*)((const char*)wlds + byte);
      acc[ct] = mfma32(wf, xq[kt], acc[ct]);
    }
  }
#pragma unroll
  for (int ct = 0; ct < 8; ++ct) {
    const int c0 = ct * 16 + 4 * g;
    const float4 bv = *(const float4*)(Qbias + c0);
    ushort4 u;
    u.x = f2b(acc[ct][0] + bv.x);
    u.y = f2b(acc[ct][1] + bv.y);
    u.z = f2b(acc[ct][2] + bv.z);
    u.w = f2b(acc[ct][3] + bv.w);
    *(ushort4*)(Qo + roff + c0) = u;
  }
}

// ---------------------------------------------------------------------------
// Attention kernel v5: 32-q chunks (16 of them, tiles = (c>>1)+1), UNIFORM
// work via pairing chunk c with 15-c in one wave => exactly 9 tiles/block.
// Grid 2048 x 64 thr; same-bh blocks differ by 256 -> same XCD. Long chunk
// first; short chunk's K/V range is a subset -> L1/L2 hot.
// ---------------------------------------------------------------------------
__global__ __launch_bounds__(64, 4) void attn_kernel(
    const unsigned short* __restrict__ Qb, const unsigned short* __restrict__ Kb,
    const unsigned short* __restrict__ Vt, float* __restrict__ out) {
  const int id = blockIdx.x;        // 0..2047
  const int pr = id >> 8;           // 0..7
  const int bh = id & 255;
  const int b = bh & 127;
  const int h = bh >> 7;

  const int lane = threadIdx.x & 63;
  const int g = lane >> 4;
  const int qi = lane & 15;

  const unsigned short* Kbb = Kb + (long)b * LL * HH + h * HDIM;
  const unsigned short* Vbase = Vt + ((long)(h * NB + b)) * HDIM * LL;

  for (int half = 0; half < 2; ++half) {
    const int c = half ? pr : 15 - pr;  // long chunk first
    const int qbase = c * 32;
    const int ntile = (c >> 1) + 1;

    bf16x8 qf[2][2];
#pragma unroll
    for (int q2 = 0; q2 < 2; ++q2) {
      const unsigned short* Qrow =
          Qb + ((long)(b * LL + qbase + q2 * 16 + qi)) * HH + h * HDIM;
      qf[q2][0] = *(const bf16x8*)(Qrow + g * 8);
      qf[q2][1] = *(const bf16x8*)(Qrow + 32 + g * 8);
    }

    f32x4 o[2][4];
#pragma unroll
    for (int q2 = 0; q2 < 2; ++q2)
#pragma unroll
      for (int dt = 0; dt < 4; ++dt) o[q2][dt] = f32x4{0.f, 0.f, 0.f, 0.f};
    float m[2] = {-1e30f, -1e30f};
    float lsum[2] = {0.f, 0.f};

    // K prefetch: tile 0
    bf16x8 kcur[4][2];
#pragma unroll
    for (int t = 0; t < 4; ++t) {
      const unsigned short* Krow = Kbb + (long)(t * 16 + qi) * HH;
      kcur[t][0] = *(const bf16x8*)(Krow + g * 8);
      kcur[t][1] = *(const bf16x8*)(Krow + 32 + g * 8);
    }

    for (int it = 0; it < ntile; ++it) {
      const int k0 = it * 64;

      bf16x8 knxt[4][2];
      if (it + 1 < ntile) {
#pragma unroll
        for (int t = 0; t < 4; ++t) {
          const unsigned short* Krow = Kbb + (long)(k0 + 64 + t * 16 + qi) * HH;
          knxt[t][0] = *(const bf16x8*)(Krow + g * 8);
          knxt[t][1] = *(const bf16x8*)(Krow + 32 + g * 8);
        }
      }

      // V loads hoisted above softmax
      bf16x4 vf[4][4];
#pragma unroll
      for (int dt = 0; dt < 4; ++dt)
#pragma unroll
        for (int t = 0; t < 4; ++t)
          vf[dt][t] = *(const bf16x4*)(Vbase + (dt * 16 + qi) * LL + k0 +
                                       t * 16 + 4 * g);

      f32x4 s[2][4];
#pragma unroll
      for (int q2 = 0; q2 < 2; ++q2)
#pragma unroll
        for (int t = 0; t < 4; ++t) {
          f32x4 acc = f32x4{0.f, 0.f, 0.f, 0.f};
          acc = mfma32(kcur[t][0], qf[q2][0], acc);
          acc = mfma32(kcur[t][1], qf[q2][1], acc);
          s[q2][t] = acc;
        }

      float alpha[2];
      bf16x4 pf[2][4];
#pragma unroll
      for (int q2 = 0; q2 < 2; ++q2) {
        const int myq = qbase + q2 * 16 + qi;
        float p[16];
        float pm = -1e30f;
#pragma unroll
        for (int t = 0; t < 4; ++t)
#pragma unroll
          for (int r = 0; r < 4; ++r) {
            float sv = s[q2][t][r] * 0.125f;    // 1/sqrt(64)
            const int key = k0 + t * 16 + 4 * g + r;
            sv = (key > myq) ? -1e30f : sv;     // causal mask
            p[t * 4 + r] = sv;
            pm = fmaxf(pm, sv);
          }
        pm = fmaxf(pm, __shfl_xor(pm, 16));
        pm = fmaxf(pm, __shfl_xor(pm, 32));
        const float mnew = fmaxf(m[q2], pm);
        alpha[q2] = exp2f((m[q2] - mnew) * 1.44269504f);
        float ps = 0.f;
#pragma unroll
        for (int i = 0; i < 16; ++i) {
          p[i] = exp2f((p[i] - mnew) * 1.44269504f);
          ps += p[i];
        }
        ps += __shfl_xor(ps, 16);
        ps += __shfl_xor(ps, 32);
        lsum[q2] = lsum[q2] * alpha[q2] + ps;
        m[q2] = mnew;
#pragma unroll
        for (int t = 0; t < 4; ++t) {
          pf[q2][t][0] = (short)f2b(p[t * 4 + 0]);
          pf[q2][t][1] = (short)f2b(p[t * 4 + 1]);
          pf[q2][t][2] = (short)f2b(p[t * 4 + 2]);
          pf[q2][t][3] = (short)f2b(p[t * 4 + 3]);
        }
      }

      float ar[2][4];
#pragma unroll
      for (int q2 = 0; q2 < 2; ++q2)
#pragma unroll
        for (int r = 0; r < 4; ++r) ar[q2][r] = __shfl(alpha[q2], 4 * g + r);

#pragma unroll
      for (int dt = 0; dt < 4; ++dt) {
#pragma unroll
        for (int q2 = 0; q2 < 2; ++q2) {
          o[q2][dt][0] *= ar[q2][0];
          o[q2][dt][1] *= ar[q2][1];
          o[q2][dt][2] *= ar[q2][2];
          o[q2][dt][3] *= ar[q2][3];
        }
#pragma unroll
        for (int t = 0; t < 4; ++t) {
          o[0][dt] = mfma16(pf[0][t], vf[dt][t], o[0][dt]);
          o[1][dt] = mfma16(pf[1][t], vf[dt][t], o[1][dt]);
        }
      }

#pragma unroll
      for (int t = 0; t < 4; ++t) {
        kcur[t][0] = knxt[t][0];
        kcur[t][1] = knxt[t][1];
      }
    }

    // epilogue
#pragma unroll
    for (int q2 = 0; q2 < 2; ++q2) {
      float linv[4];
#pragma unroll
      for (int r = 0; r < 4; ++r) linv[r] = 1.0f / __shfl(lsum[q2], 4 * g + r);
#pragma unroll
      for (int dt = 0; dt < 4; ++dt)
#pragma unroll
        for (int r = 0; r < 4; ++r) {
          const long row = (long)(b * LL + qbase + q2 * 16 + 4 * g + r);
          out[row * HH + h * HDIM + dt * 16 + qi] = o[q2][dt][r] * linv[r];
        }
    }
  }
}

extern "C" void kernel_launch(void* const* d_in, const int* in_sizes, int n_in,
                              void* d_out, int out_size, void* d_ws, size_t ws_size,
                              hipStream_t stream) {
  const float* queries = (const float*)d_in[0];
  const float* keys    = (const float*)d_in[1];
  const float* nbr     = (const float*)d_in[2];
  const float* nat     = (const float*)d_in[3];
  const float* pk      = (const float*)d_in[4];
  const float* pv      = (const float*)d_in[5];
  const float* Qw      = (const float*)d_in[6];
  const float* Qbias   = (const float*)d_in[7];
  const float* Kw      = (const float*)d_in[8];
  const float* Kbias   = (const float*)d_in[9];
  const float* Vw      = (const float*)d_in[10];
  const float* Vbias   = (const float*)d_in[11];
  // d_in[12] = attn_mask: exact causal ~tril, computed analytically in-kernel.

  unsigned short* Qo = (unsigned short*)d_ws;
  unsigned short* Ko = Qo + (size_t)NROWS * HH;
  unsigned short* Vt = Ko + (size_t)NROWS * HH;
  unsigned short* Wb = Vt + (size_t)NROWS * HH;  // [3][128][128] bf16, linear

  wcvt_kernel<<<48, 256, 0, stream>>>(Qw, Kw, Vw, Wb);

  kv_proj_kernel<<<NROWS / 128, 512, 0, stream>>>(keys, nbr, nat, pk, pv, Wb,
                                                  Kbias, Vbias, Ko, Vt);
  q_proj_kernel<<<NROWS / 128, 512, 0, stream>>>(queries, Wb, Qbias, Qo);

  attn_kernel<<<2048, 64, 0, stream>>>(Qo, Ko, Vt, (float*)d_out);
}

// Round 11
// 122.435 us; speedup vs baseline: 1.3926x; 1.3926x over previous
//
#include <hip/hip_runtime.h>

typedef __attribute__((ext_vector_type(8))) short bf16x8;
typedef __attribute__((ext_vector_type(4))) short bf16x4;
typedef __attribute__((ext_vector_type(4))) float f32x4;

#define NB 128
#define LL 512
#define HH 128
#define HDIM 64
#define NROWS (NB * LL)  // 65536

__device__ __forceinline__ unsigned short f2b(float f) {
  unsigned int x = __float_as_uint(f);
  x = (x + 0x7fffu + ((x >> 16) & 1u)) >> 16;  // RNE
  return (unsigned short)x;
}

__device__ __forceinline__ bf16x8 load8_cvt(const float* p) {
  float4 a = *(const float4*)p;
  float4 b = *(const float4*)(p + 4);
  bf16x8 r;
  r[0] = (short)f2b(a.x); r[1] = (short)f2b(a.y);
  r[2] = (short)f2b(a.z); r[3] = (short)f2b(a.w);
  r[4] = (short)f2b(b.x); r[5] = (short)f2b(b.y);
  r[6] = (short)f2b(b.z); r[7] = (short)f2b(b.w);
  return r;
}

#if __has_builtin(__builtin_amdgcn_mfma_f32_16x16x16bf16_1k)
__device__ __forceinline__ f32x4 mfma16(bf16x4 a, bf16x4 b, f32x4 c) {
  return __builtin_amdgcn_mfma_f32_16x16x16bf16_1k(a, b, c, 0, 0, 0);
}
#else
__device__ __forceinline__ f32x4 mfma16(bf16x4 a, bf16x4 b, f32x4 c) {
  asm volatile("s_nop 1\n\t"
               "v_mfma_f32_16x16x16_bf16 %0, %1, %2, %0\n\t"
               "s_nop 7\n\t"
               "s_nop 7"
               : "+v"(c) : "v"(a), "v"(b));
  return c;
}
#endif

__device__ __forceinline__ f32x4 mfma32(bf16x8 a, bf16x8 b, f32x4 c) {
  return __builtin_amdgcn_mfma_f32_16x16x32_bf16(a, b, c, 0, 0, 0);
}

// ---------------------------------------------------------------------------
// Weight pre-convert: fp32 -> bf16, LINEAR layout Wb[3][128][128] (Q,K,V).
// ---------------------------------------------------------------------------
__global__ __launch_bounds__(256) void wcvt_kernel(
    const float* __restrict__ Qw, const float* __restrict__ Kw,
    const float* __restrict__ Vw, unsigned short* __restrict__ Wb) {
  const int i = blockIdx.x * 256 + threadIdx.x;  // 0..12287 float4s
  const float* src = (i < 4096) ? Qw : (i < 8192) ? Kw : Vw;
  const int off = (i & 4095) << 2;
  float4 v = *(const float4*)(src + off);
  ushort4 u;
  u.x = f2b(v.x); u.y = f2b(v.y); u.z = f2b(v.z); u.w = f2b(v.w);
  *(ushort4*)(Wb + ((size_t)i << 2)) = u;
}

// ---------------------------------------------------------------------------
// KV projection v4: col-split for low VGPR + high occupancy.
// 1024 thr = 16 waves; wave (rg = w>>1, ch = w&1) computes 16 rows x 64 cols
// (cols ch*64..ch*64+63). Kw+Vw in 64KB LDS (swizzled) -> 2 blocks/CU,
// 32 waves/CU IF VGPR <= 64 (col-split halves acc/epilogue state).
// Grid: 512 blocks x 128 rows.
// ---------------------------------------------------------------------------
__global__ __launch_bounds__(1024) void kv_proj_kernel(
    const float* __restrict__ keys, const float* __restrict__ nbr,
    const float* __restrict__ nat, const float* __restrict__ pk,
    const float* __restrict__ pv, const unsigned short* __restrict__ Wb,
    const float* __restrict__ Kbias, const float* __restrict__ Vbias,
    unsigned short* __restrict__ Ko, unsigned short* __restrict__ Vt) {
  __shared__ unsigned short wlds[2 * 128 * 128];  // 64 KB: Kw, Vw (swizzled)

  const int tid = threadIdx.x;
  const int lane = tid & 63;
  const int wave = tid >> 6;
  const int g = lane >> 4;
  const int qi = lane & 15;

  // stage Kw,Vw (bf16, swizzle byte ^= ((row&7)<<4)); 4 x 16B per thread
#pragma unroll
  for (int i = 0; i < 4; ++i) {
    const int byte = (tid + i * 1024) * 16;  // [0, 65536)
    const int row = (byte >> 8) & 127;
    *(bf16x8*)((char*)wlds + (byte ^ ((row & 7) << 4))) =
        *(const bf16x8*)((const char*)Wb + 32768 + byte);
  }

  const int rg = wave >> 1;        // 0..7  row group
  const int ch = wave & 1;         // 0..1  col half (= head for V)
  const long row = (long)blockIdx.x * 128 + rg * 16 + qi;
  const int rswz = (qi & 7) << 4;
  const long roff = row * 128;

  // X fragment (B operand): issued before barrier to overlap staging
  bf16x8 xk[4];
#pragma unroll
  for (int kt = 0; kt < 4; ++kt)
    xk[kt] = load8_cvt(keys + roff + kt * 32 + g * 8);

  __syncthreads();

  // ---- K projection (Kw at LDS offset 0) ----
  f32x4 accK[4];
#pragma unroll
  for (int ct = 0; ct < 4; ++ct) {
    accK[ct] = f32x4{0.f, 0.f, 0.f, 0.f};
    const int rw = ch * 64 + ct * 16 + qi;  // W row = out col
#pragma unroll
    for (int kt = 0; kt < 4; ++kt) {
      const int byte = rw * 256 + ((kt * 64 + g * 16) ^ rswz);
      bf16x8 wf = *(const bf16x8*)((const char*)wlds + byte);
      accK[ct] = mfma32(wf, xk[kt], accK[ct]);
    }
  }

  float4 tmp[4];  // nbr+nat carried to V epilogue
#pragma unroll
  for (int ct = 0; ct < 4; ++ct) {
    const int c0 = ch * 64 + ct * 16 + 4 * g;
    const float4 bv = *(const float4*)(Kbias + c0);
    const float4 nb = *(const float4*)(nbr + roff + c0);
    const float4 na = *(const float4*)(nat + roff + c0);
    const float4 p4 = *(const float4*)(pk + roff + c0);
    float4 t;
    t.x = nb.x + na.x; t.y = nb.y + na.y; t.z = nb.z + na.z; t.w = nb.w + na.w;
    tmp[ct] = t;
    ushort4 u;
    u.x = f2b(accK[ct][0] + bv.x + t.x + p4.x);
    u.y = f2b(accK[ct][1] + bv.y + t.y + p4.y);
    u.z = f2b(accK[ct][2] + bv.z + t.z + p4.z);
    u.w = f2b(accK[ct][3] + bv.w + t.w + p4.w);
    *(ushort4*)(Ko + roff + c0) = u;
  }

  // ---- V projection (Vw at LDS offset 32768) ----
  f32x4 accV[4];
#pragma unroll
  for (int ct = 0; ct < 4; ++ct) {
    accV[ct] = f32x4{0.f, 0.f, 0.f, 0.f};
    const int rw = ch * 64 + ct * 16 + qi;
#pragma unroll
    for (int kt = 0; kt < 4; ++kt) {
      const int byte = 32768 + rw * 256 + ((kt * 64 + g * 16) ^ rswz);
      bf16x8 wf = *(const bf16x8*)((const char*)wlds + byte);
      accV[ct] = mfma32(wf, xk[kt], accV[ct]);
    }
  }

  const long bidx = row >> 9, lrow = row & 511;
  unsigned short* vbase = Vt + ((long)ch * NB + bidx) * HDIM * LL + lrow;
#pragma unroll
  for (int ct = 0; ct < 4; ++ct) {
    const int c0 = ch * 64 + ct * 16 + 4 * g;
    const float4 bv = *(const float4*)(Vbias + c0);
    const float4 p4 = *(const float4*)(pv + roff + c0);
    const int d0 = ct * 16 + 4 * g;
    unsigned short* vp = vbase + (long)d0 * LL;
    vp[0 * LL] = f2b(accV[ct][0] + bv.x + tmp[ct].x + p4.x);
    vp[1 * LL] = f2b(accV[ct][1] + bv.y + tmp[ct].y + p4.y);
    vp[2 * LL] = f2b(accV[ct][2] + bv.z + tmp[ct].z + p4.z);
    vp[3 * LL] = f2b(accV[ct][3] + bv.w + tmp[ct].w + p4.w);
  }
}

// ---------------------------------------------------------------------------
// Q projection (R7 version): Qw in 32KB LDS.
// ---------------------------------------------------------------------------
__global__ __launch_bounds__(512) void q_proj_kernel(
    const float* __restrict__ queries, const unsigned short* __restrict__ Wb,
    const float* __restrict__ Qbias, unsigned short* __restrict__ Qo) {
  __shared__ unsigned short wlds[128 * 128];  // 32 KB

  const int tid = threadIdx.x;
  const int lane = tid & 63;
  const int wave = tid >> 6;
  const int g = lane >> 4, qi = lane & 15;

#pragma unroll
  for (int i = 0; i < 4; ++i) {
    const int byte = (tid + i * 512) * 16;
    const int row = (byte >> 8) & 127;
    *(bf16x8*)((char*)wlds + (byte ^ ((row & 7) << 4))) =
        *(const bf16x8*)((const char*)Wb + byte);
  }

  const long row = (long)blockIdx.x * 128 + wave * 16 + qi;
  const int rswz = (qi & 7) << 4;
  const long roff = row * 128;

  bf16x8 xq[4];
#pragma unroll
  for (int kt = 0; kt < 4; ++kt)
    xq[kt] = load8_cvt(queries + roff + kt * 32 + g * 8);

  __syncthreads();

  f32x4 acc[8];
#pragma unroll
  for (int ct = 0; ct < 8; ++ct) {
    acc[ct] = f32x4{0.f, 0.f, 0.f, 0.f};
#pragma unroll
    for (int kt = 0; kt < 4; ++kt) {
      const int byte = (ct * 16 + qi) * 256 + ((kt * 64 + g * 16) ^ rswz);
      bf16x8 wf = *(const bf16x8*)((const char*)wlds + byte);
      acc[ct] = mfma32(wf, xq[kt], acc[ct]);
    }
  }
#pragma unroll
  for (int ct = 0; ct < 8; ++ct) {
    const int c0 = ct * 16 + 4 * g;
    const float4 bv = *(const float4*)(Qbias + c0);
    ushort4 u;
    u.x = f2b(acc[ct][0] + bv.x);
    u.y = f2b(acc[ct][1] + bv.y);
    u.z = f2b(acc[ct][2] + bv.z);
    u.w = f2b(acc[ct][3] + bv.w);
    *(ushort4*)(Qo + roff + c0) = u;
  }
}

// ---------------------------------------------------------------------------
// Attention kernel (exact R6/R7 version — the proven one, no VGPR cap):
// 1-wave blocks, LPT dispatch, K double-buffer, V hoisted, swapped QK^T.
// ---------------------------------------------------------------------------
__global__ __launch_bounds__(64) void attn_kernel(
    const unsigned short* __restrict__ Qb, const unsigned short* __restrict__ Kb,
    const unsigned short* __restrict__ Vt, float* __restrict__ out) {
  const int id = blockIdx.x;        // 0..4095
  const int c = 15 - (id >> 8);     // chunk (longest first for LPT)
  const int bh = id & 255;
  const int b = bh & 127;
  const int h = bh >> 7;

  const int lane = threadIdx.x;     // 0..63
  const int g = lane >> 4;
  const int qi = lane & 15;
  const int qbase = c * 32;

  bf16x8 qf[2][2];
#pragma unroll
  for (int q2 = 0; q2 < 2; ++q2) {
    const unsigned short* Qrow =
        Qb + ((long)(b * LL + qbase + q2 * 16 + qi)) * HH + h * HDIM;
    qf[q2][0] = *(const bf16x8*)(Qrow + g * 8);
    qf[q2][1] = *(const bf16x8*)(Qrow + 32 + g * 8);
  }

  f32x4 o[2][4];
#pragma unroll
  for (int q2 = 0; q2 < 2; ++q2)
#pragma unroll
    for (int dt = 0; dt < 4; ++dt) o[q2][dt] = f32x4{0.f, 0.f, 0.f, 0.f};
  float m[2] = {-1e30f, -1e30f};
  float lsum[2] = {0.f, 0.f};

  const int ntile = (c >> 1) + 1;   // causal
  const unsigned short* Kbb = Kb + (long)b * LL * HH + h * HDIM;
  const unsigned short* Vbase = Vt + ((long)(h * NB + b)) * HDIM * LL;

  bf16x8 kcur[4][2];
#pragma unroll
  for (int t = 0; t < 4; ++t) {
    const unsigned short* Krow = Kbb + (long)(t * 16 + qi) * HH;
    kcur[t][0] = *(const bf16x8*)(Krow + g * 8);
    kcur[t][1] = *(const bf16x8*)(Krow + 32 + g * 8);
  }

  for (int it = 0; it < ntile; ++it) {
    const int k0 = it * 64;

    bf16x8 knxt[4][2];
    if (it + 1 < ntile) {
#pragma unroll
      for (int t = 0; t < 4; ++t) {
        const unsigned short* Krow = Kbb + (long)(k0 + 64 + t * 16 + qi) * HH;
        knxt[t][0] = *(const bf16x8*)(Krow + g * 8);
        knxt[t][1] = *(const bf16x8*)(Krow + 32 + g * 8);
      }
    }

    bf16x4 vf[4][4];
#pragma unroll
    for (int dt = 0; dt < 4; ++dt)
#pragma unroll
      for (int t = 0; t < 4; ++t)
        vf[dt][t] =
            *(const bf16x4*)(Vbase + (dt * 16 + qi) * LL + k0 + t * 16 + 4 * g);

    f32x4 s[2][4];
#pragma unroll
    for (int q2 = 0; q2 < 2; ++q2)
#pragma unroll
      for (int t = 0; t < 4; ++t) {
        f32x4 acc = f32x4{0.f, 0.f, 0.f, 0.f};
        acc = mfma32(kcur[t][0], qf[q2][0], acc);
        acc = mfma32(kcur[t][1], qf[q2][1], acc);
        s[q2][t] = acc;
      }

    float alpha[2];
    bf16x4 pf[2][4];
#pragma unroll
    for (int q2 = 0; q2 < 2; ++q2) {
      const int myq = qbase + q2 * 16 + qi;
      float p[16];
      float pm = -1e30f;
#pragma unroll
      for (int t = 0; t < 4; ++t)
#pragma unroll
        for (int r = 0; r < 4; ++r) {
          float sv = s[q2][t][r] * 0.125f;      // 1/sqrt(64)
          const int key = k0 + t * 16 + 4 * g + r;
          sv = (key > myq) ? -1e30f : sv;       // causal mask
          p[t * 4 + r] = sv;
          pm = fmaxf(pm, sv);
        }
      pm = fmaxf(pm, __shfl_xor(pm, 16));
      pm = fmaxf(pm, __shfl_xor(pm, 32));
      const float mnew = fmaxf(m[q2], pm);
      alpha[q2] = exp2f((m[q2] - mnew) * 1.44269504f);
      float ps = 0.f;
#pragma unroll
      for (int i = 0; i < 16; ++i) {
        p[i] = exp2f((p[i] - mnew) * 1.44269504f);
        ps += p[i];
      }
      ps += __shfl_xor(ps, 16);
      ps += __shfl_xor(ps, 32);
      lsum[q2] = lsum[q2] * alpha[q2] + ps;
      m[q2] = mnew;
#pragma unroll
      for (int t = 0; t < 4; ++t) {
        pf[q2][t][0] = (short)f2b(p[t * 4 + 0]);
        pf[q2][t][1] = (short)f2b(p[t * 4 + 1]);
        pf[q2][t][2] = (short)f2b(p[t * 4 + 2]);
        pf[q2][t][3] = (short)f2b(p[t * 4 + 3]);
      }
    }

    float ar[2][4];
#pragma unroll
    for (int q2 = 0; q2 < 2; ++q2)
#pragma unroll
      for (int r = 0; r < 4; ++r) ar[q2][r] = __shfl(alpha[q2], 4 * g + r);

#pragma unroll
    for (int dt = 0; dt < 4; ++dt) {
#pragma unroll
      for (int q2 = 0; q2 < 2; ++q2) {
        o[q2][dt][0] *= ar[q2][0];
        o[q2][dt][1] *= ar[q2][1];
        o[q2][dt][2] *= ar[q2][2];
        o[q2][dt][3] *= ar[q2][3];
      }
#pragma unroll
      for (int t = 0; t < 4; ++t) {
        o[0][dt] = mfma16(pf[0][t], vf[dt][t], o[0][dt]);
        o[1][dt] = mfma16(pf[1][t], vf[dt][t], o[1][dt]);
      }
    }

#pragma unroll
    for (int t = 0; t < 4; ++t) {
      kcur[t][0] = knxt[t][0];
      kcur[t][1] = knxt[t][1];
    }
  }

#pragma unroll
  for (int q2 = 0; q2 < 2; ++q2) {
    float linv[4];
#pragma unroll
    for (int r = 0; r < 4; ++r) linv[r] = 1.0f / __shfl(lsum[q2], 4 * g + r);
#pragma unroll
    for (int dt = 0; dt < 4; ++dt)
#pragma unroll
      for (int r = 0; r < 4; ++r) {
        const long row = (long)(b * LL + qbase + q2 * 16 + 4 * g + r);
        out[row * HH + h * HDIM + dt * 16 + qi] = o[q2][dt][r] * linv[r];
      }
  }
}

extern "C" void kernel_launch(void* const* d_in, const int* in_sizes, int n_in,
                              void* d_out, int out_size, void* d_ws, size_t ws_size,
                              hipStream_t stream) {
  const float* queries = (const float*)d_in[0];
  const float* keys    = (const float*)d_in[1];
  const float* nbr     = (const float*)d_in[2];
  const float* nat     = (const float*)d_in[3];
  const float* pk      = (const float*)d_in[4];
  const float* pv      = (const float*)d_in[5];
  const float* Qw      = (const float*)d_in[6];
  const float* Qbias   = (const float*)d_in[7];
  const float* Kw      = (const float*)d_in[8];
  const float* Kbias   = (const float*)d_in[9];
  const float* Vw      = (const float*)d_in[10];
  const float* Vbias   = (const float*)d_in[11];
  // d_in[12] = attn_mask: exact causal ~tril, computed analytically in-kernel.

  unsigned short* Qo = (unsigned short*)d_ws;
  unsigned short* Ko = Qo + (size_t)NROWS * HH;
  unsigned short* Vt = Ko + (size_t)NROWS * HH;
  unsigned short* Wb = Vt + (size_t)NROWS * HH;  // [3][128][128] bf16, linear

  wcvt_kernel<<<48, 256, 0, stream>>>(Qw, Kw, Vw, Wb);

  kv_proj_kernel<<<NROWS / 128, 1024, 0, stream>>>(keys, nbr, nat, pk, pv, Wb,
                                                   Kbias, Vbias, Ko, Vt);
  q_proj_kernel<<<NROWS / 128, 512, 0, stream>>>(queries, Wb, Qbias, Qo);

  attn_kernel<<<4096, 64, 0, stream>>>(Qo, Ko, Vt, (float*)d_out);
}

// Round 13
// 121.175 us; speedup vs baseline: 1.4071x; 1.0104x over previous
//
#include <hip/hip_runtime.h>

typedef __attribute__((ext_vector_type(8))) short bf16x8;
typedef __attribute__((ext_vector_type(4))) short bf16x4;
typedef __attribute__((ext_vector_type(4))) float f32x4;

#define NB 128
#define LL 512
#define HH 128
#define HDIM 64
#define NROWS (NB * LL)  // 65536

__device__ __forceinline__ unsigned short f2b(float f) {
  unsigned int x = __float_as_uint(f);
  x = (x + 0x7fffu + ((x >> 16) & 1u)) >> 16;  // RNE
  return (unsigned short)x;
}

__device__ __forceinline__ bf16x8 load8_cvt(const float* p) {
  float4 a = *(const float4*)p;
  float4 b = *(const float4*)(p + 4);
  bf16x8 r;
  r[0] = (short)f2b(a.x); r[1] = (short)f2b(a.y);
  r[2] = (short)f2b(a.z); r[3] = (short)f2b(a.w);
  r[4] = (short)f2b(b.x); r[5] = (short)f2b(b.y);
  r[6] = (short)f2b(b.z); r[7] = (short)f2b(b.w);
  return r;
}

#if __has_builtin(__builtin_amdgcn_mfma_f32_16x16x16bf16_1k)
__device__ __forceinline__ f32x4 mfma16(bf16x4 a, bf16x4 b, f32x4 c) {
  return __builtin_amdgcn_mfma_f32_16x16x16bf16_1k(a, b, c, 0, 0, 0);
}
#else
__device__ __forceinline__ f32x4 mfma16(bf16x4 a, bf16x4 b, f32x4 c) {
  asm volatile("s_nop 1\n\t"
               "v_mfma_f32_16x16x16_bf16 %0, %1, %2, %0\n\t"
               "s_nop 7\n\t"
               "s_nop 7"
               : "+v"(c) : "v"(a), "v"(b));
  return c;
}
#endif

__device__ __forceinline__ f32x4 mfma32(bf16x8 a, bf16x8 b, f32x4 c) {
  return __builtin_amdgcn_mfma_f32_16x16x32_bf16(a, b, c, 0, 0, 0);
}

// pinned 16B load: cannot be sunk by the compiler (asm volatile)
#define GLOAD(dst, base, OFF)                                        \
  asm volatile("global_load_dwordx4 %0, %1, off offset:" #OFF        \
               : "=v"(dst) : "v"(base))

// counted wait; sched_barrier(0) stops the MI scheduler from hoisting the
// register-consuming arithmetic above the wait (guide rule 18 pattern).
#define VWAIT(N)                                                     \
  asm volatile("s_waitcnt vmcnt(" #N ")" ::: "memory");              \
  __builtin_amdgcn_sched_barrier(0)

// ---------------------------------------------------------------------------
// Weight pre-convert: fp32 -> bf16, LINEAR layout Wb[3][128][128] (Q,K,V).
// ---------------------------------------------------------------------------
__global__ __launch_bounds__(256) void wcvt_kernel(
    const float* __restrict__ Qw, const float* __restrict__ Kw,
    const float* __restrict__ Vw, unsigned short* __restrict__ Wb) {
  const int i = blockIdx.x * 256 + threadIdx.x;  // 0..12287 float4s
  const float* src = (i < 4096) ? Qw : (i < 8192) ? Kw : Vw;
  const int off = (i & 4095) << 2;
  float4 v = *(const float4*)(src + off);
  ushort4 u;
  u.x = f2b(v.x); u.y = f2b(v.y); u.z = f2b(v.z); u.w = f2b(v.w);
  *(ushort4*)(Wb + ((size_t)i << 2)) = u;
}

// ---------------------------------------------------------------------------
// KV projection v6b: col-split + asm-pinned load pipeline (counted vmcnt).
//   Ko = keys@Kw^T + nbr + nat + pk      (NO Kbias: softmax-invariant)
//   Vt = (keys@Vw^T + nbr + nat + pv)^T  (NO Vbias: added in attn epilogue)
// 512 thr = 8 waves: wave (rg=w>>1, ch=w&1) -> 16 rows x 64 cols.
// Kw+Vw in 64KB LDS (swizzled). Grid 1024 blocks x 64 rows.
// ---------------------------------------------------------------------------
__global__ __launch_bounds__(512) void kv_proj_kernel(
    const float* __restrict__ keys, const float* __restrict__ nbr,
    const float* __restrict__ nat, const float* __restrict__ pk,
    const float* __restrict__ pv, const unsigned short* __restrict__ Wb,
    unsigned short* __restrict__ Ko, unsigned short* __restrict__ Vt) {
  __shared__ unsigned short wlds[2 * 128 * 128];  // 64 KB: Kw, Vw (swizzled)

  const int tid = threadIdx.x;
  const int lane = tid & 63;
  const int wave = tid >> 6;
  const int g = lane >> 4;
  const int qi = lane & 15;

  // stage Kw,Vw (bf16, swizzle byte ^= ((row&7)<<4)); 8 x 16B per thread
#pragma unroll
  for (int i = 0; i < 8; ++i) {
    const int byte = (tid + i * 512) * 16;  // [0, 65536)
    const int row = (byte >> 8) & 127;
    *(bf16x8*)((char*)wlds + (byte ^ ((row & 7) << 4))) =
        *(const bf16x8*)((const char*)Wb + 32768 + byte);
  }

  const int rg = wave >> 1;  // 0..3
  const int ch = wave & 1;   // 0..1 col half (= head for V)
  const long row = (long)blockIdx.x * 64 + rg * 16 + qi;
  const int rswz = (qi & 7) << 4;
  const long roff = row * 128;

  // keys loads (HIP) before barrier: fly during LDS staging, drained by it
  bf16x8 xk[4];
#pragma unroll
  for (int kt = 0; kt < 4; ++kt)
    xk[kt] = load8_cvt(keys + roff + kt * 32 + g * 8);

  __syncthreads();

  // base pointers for the pinned streams (lane's 16B at ct=0; +64B per ct)
  const float* bnb = nbr + roff + ch * 64 + 4 * g;
  const float* bna = nat + roff + ch * 64 + 4 * g;
  const float* bpk = pk + roff + ch * 64 + 4 * g;
  const float* bpv = pv + roff + ch * 64 + 4 * g;

  float4 nb0, na0, k0, nb1, na1, k1, nb2, na2, k2, nb3, na3, k3;
  // --- issue 12 pinned loads (outstanding: 12) ---
  GLOAD(nb0, bnb, 0);   GLOAD(na0, bna, 0);   GLOAD(k0, bpk, 0);
  GLOAD(nb1, bnb, 64);  GLOAD(na1, bna, 64);  GLOAD(k1, bpk, 64);
  GLOAD(nb2, bnb, 128); GLOAD(na2, bna, 128); GLOAD(k2, bpk, 128);
  GLOAD(nb3, bnb, 192); GLOAD(na3, bna, 192); GLOAD(k3, bpk, 192);

  // --- MFMA K (LDS, lgkmcnt only) ---
  f32x4 accK[4];
#pragma unroll
  for (int ct = 0; ct < 4; ++ct) {
    accK[ct] = f32x4{0.f, 0.f, 0.f, 0.f};
    const int rw = ch * 64 + ct * 16 + qi;  // W row = out col
#pragma unroll
    for (int kt = 0; kt < 4; ++kt) {
      const int byte = rw * 256 + ((kt * 64 + g * 16) ^ rswz);
      bf16x8 wf = *(const bf16x8*)((const char*)wlds + byte);
      accK[ct] = mfma32(wf, xk[kt], accK[ct]);
    }
  }

  float4 tmp[4];
  // --- K epilogue, counted waits (stores count toward vmcnt too) ---
  // KEPI(0): 12 outstanding, need first 3 -> vmcnt(9).
  // KEPI(1): 6 loads remain newer + 1 store -> vmcnt(7). etc.
#define KEPI(ct, NB_, NA_, PK_, W)                                   \
  {                                                                  \
    VWAIT(W);                                                        \
    const int c0 = ch * 64 + (ct) * 16 + 4 * g;                      \
    float4 t;                                                        \
    t.x = NB_.x + NA_.x; t.y = NB_.y + NA_.y;                        \
    t.z = NB_.z + NA_.z; t.w = NB_.w + NA_.w;                        \
    tmp[ct] = t;                                                     \
    ushort4 u;                                                       \
    u.x = f2b(accK[ct][0] + t.x + PK_.x);                            \
    u.y = f2b(accK[ct][1] + t.y + PK_.y);                            \
    u.z = f2b(accK[ct][2] + t.z + PK_.z);                            \
    u.w = f2b(accK[ct][3] + t.w + PK_.w);                            \
    *(ushort4*)(Ko + roff + c0) = u;                                 \
  }
  KEPI(0, nb0, na0, k0, 9);
  KEPI(1, nb1, na1, k1, 7);
  KEPI(2, nb2, na2, k2, 5);
  KEPI(3, nb3, na3, k3, 3);

  // --- issue pv loads ---
  float4 v0, v1, v2, v3;
  GLOAD(v0, bpv, 0); GLOAD(v1, bpv, 64); GLOAD(v2, bpv, 128); GLOAD(v3, bpv, 192);

  // --- MFMA V ---
  f32x4 accV[4];
#pragma unroll
  for (int ct = 0; ct < 4; ++ct) {
    accV[ct] = f32x4{0.f, 0.f, 0.f, 0.f};
    const int rw = ch * 64 + ct * 16 + qi;
#pragma unroll
    for (int kt = 0; kt < 4; ++kt) {
      const int byte = 32768 + rw * 256 + ((kt * 64 + g * 16) ^ rswz);
      bf16x8 wf = *(const bf16x8*)((const char*)wlds + byte);
      accV[ct] = mfma32(wf, xk[kt], accV[ct]);
    }
  }

  const long bidx = row >> 9, lrow = row & 511;
  unsigned short* vbase = Vt + ((long)ch * NB + bidx) * HDIM * LL + lrow;
  // VEPI(0): newer than v0 = {v1,v2,v3} -> vmcnt(3).
  // VEPI(1): newer than v1 = {v2,v3} + 4 Vt scalar stores -> vmcnt(6). etc.
#define VEPI(ct, PV_, W)                                             \
  {                                                                  \
    VWAIT(W);                                                        \
    const int d0 = (ct) * 16 + 4 * g;                                \
    unsigned short* vp = vbase + (long)d0 * LL;                      \
    vp[0 * LL] = f2b(accV[ct][0] + tmp[ct].x + PV_.x);               \
    vp[1 * LL] = f2b(accV[ct][1] + tmp[ct].y + PV_.y);               \
    vp[2 * LL] = f2b(accV[ct][2] + tmp[ct].z + PV_.z);               \
    vp[3 * LL] = f2b(accV[ct][3] + tmp[ct].w + PV_.w);               \
  }
  VEPI(0, v0, 3);
  VEPI(1, v1, 6);
  VEPI(2, v2, 9);
  VEPI(3, v3, 12);
}

// ---------------------------------------------------------------------------
// Q projection (R7 version): Qw in 32KB LDS. Keeps Qbias (not removable).
// ---------------------------------------------------------------------------
__global__ __launch_bounds__(512) void q_proj_kernel(
    const float* __restrict__ queries, const unsigned short* __restrict__ Wb,
    const float* __restrict__ Qbias, unsigned short* __restrict__ Qo) {
  __shared__ unsigned short wlds[128 * 128];  // 32 KB

  const int tid = threadIdx.x;
  const int lane = tid & 63;
  const int wave = tid >> 6;
  const int g = lane >> 4, qi = lane & 15;

#pragma unroll
  for (int i = 0; i < 4; ++i) {
    const int byte = (tid + i * 512) * 16;
    const int row = (byte >> 8) & 127;
    *(bf16x8*)((char*)wlds + (byte ^ ((row & 7) << 4))) =
        *(const bf16x8*)((const char*)Wb + byte);
  }

  const long row = (long)blockIdx.x * 128 + wave * 16 + qi;
  const int rswz = (qi & 7) << 4;
  const long roff = row * 128;

  bf16x8 xq[4];
#pragma unroll
  for (int kt = 0; kt < 4; ++kt)
    xq[kt] = load8_cvt(queries + roff + kt * 32 + g * 8);

  __syncthreads();

  f32x4 acc[8];
#pragma unroll
  for (int ct = 0; ct < 8; ++ct) {
    acc[ct] = f32x4{0.f, 0.f, 0.f, 0.f};
#pragma unroll
    for (int kt = 0; kt < 4; ++kt) {
      const int byte = (ct * 16 + qi) * 256 + ((kt * 64 + g * 16) ^ rswz);
      bf16x8 wf = *(const bf16x8*)((const char*)wlds + byte);
      acc[ct] = mfma32(wf, xq[kt], acc[ct]);
    }
  }
#pragma unroll
  for (int ct = 0; ct < 8; ++ct) {
    const int c0 = ct * 16 + 4 * g;
    const float4 bv = *(const float4*)(Qbias + c0);
    ushort4 u;
    u.x = f2b(acc[ct][0] + bv.x);
    u.y = f2b(acc[ct][1] + bv.y);
    u.z = f2b(acc[ct][2] + bv.z);
    u.w = f2b(acc[ct][3] + bv.w);
    *(ushort4*)(Qo + roff + c0) = u;
  }
}

// ---------------------------------------------------------------------------
// Attention kernel (R6/R7 proven version) + Vbias added in the epilogue
// (out = attn(V') + Vb exactly, since softmax weights sum to 1).
// ---------------------------------------------------------------------------
__global__ __launch_bounds__(64) void attn_kernel(
    const unsigned short* __restrict__ Qb, const unsigned short* __restrict__ Kb,
    const unsigned short* __restrict__ Vt, const float* __restrict__ Vbias,
    float* __restrict__ out) {
  const int id = blockIdx.x;        // 0..4095
  const int c = 15 - (id >> 8);     // chunk (longest first for LPT)
  const int bh = id & 255;
  const int b = bh & 127;
  const int h = bh >> 7;

  const int lane = threadIdx.x;     // 0..63
  const int g = lane >> 4;
  const int qi = lane & 15;
  const int qbase = c * 32;

  bf16x8 qf[2][2];
#pragma unroll
  for (int q2 = 0; q2 < 2; ++q2) {
    const unsigned short* Qrow =
        Qb + ((long)(b * LL + qbase + q2 * 16 + qi)) * HH + h * HDIM;
    qf[q2][0] = *(const bf16x8*)(Qrow + g * 8);
    qf[q2][1] = *(const bf16x8*)(Qrow + 32 + g * 8);
  }

  float vbe[4];
#pragma unroll
  for (int dt = 0; dt < 4; ++dt) vbe[dt] = Vbias[h * HDIM + dt * 16 + qi];

  f32x4 o[2][4];
#pragma unroll
  for (int q2 = 0; q2 < 2; ++q2)
#pragma unroll
    for (int dt = 0; dt < 4; ++dt) o[q2][dt] = f32x4{0.f, 0.f, 0.f, 0.f};
  float m[2] = {-1e30f, -1e30f};
  float lsum[2] = {0.f, 0.f};

  const int ntile = (c >> 1) + 1;   // causal
  const unsigned short* Kbb = Kb + (long)b * LL * HH + h * HDIM;
  const unsigned short* Vbase = Vt + ((long)(h * NB + b)) * HDIM * LL;

  bf16x8 kcur[4][2];
#pragma unroll
  for (int t = 0; t < 4; ++t) {
    const unsigned short* Krow = Kbb + (long)(t * 16 + qi) * HH;
    kcur[t][0] = *(const bf16x8*)(Krow + g * 8);
    kcur[t][1] = *(const bf16x8*)(Krow + 32 + g * 8);
  }

  for (int it = 0; it < ntile; ++it) {
    const int k0 = it * 64;

    bf16x8 knxt[4][2];
    if (it + 1 < ntile) {
#pragma unroll
      for (int t = 0; t < 4; ++t) {
        const unsigned short* Krow = Kbb + (long)(k0 + 64 + t * 16 + qi) * HH;
        knxt[t][0] = *(const bf16x8*)(Krow + g * 8);
        knxt[t][1] = *(const bf16x8*)(Krow + 32 + g * 8);
      }
    }

    bf16x4 vf[4][4];
#pragma unroll
    for (int dt = 0; dt < 4; ++dt)
#pragma unroll
      for (int t = 0; t < 4; ++t)
        vf[dt][t] =
            *(const bf16x4*)(Vbase + (dt * 16 + qi) * LL + k0 + t * 16 + 4 * g);

    f32x4 s[2][4];
#pragma unroll
    for (int q2 = 0; q2 < 2; ++q2)
#pragma unroll
      for (int t = 0; t < 4; ++t) {
        f32x4 acc = f32x4{0.f, 0.f, 0.f, 0.f};
        acc = mfma32(kcur[t][0], qf[q2][0], acc);
        acc = mfma32(kcur[t][1], qf[q2][1], acc);
        s[q2][t] = acc;
      }

    float alpha[2];
    bf16x4 pf[2][4];
#pragma unroll
    for (int q2 = 0; q2 < 2; ++q2) {
      const int myq = qbase + q2 * 16 + qi;
      float p[16];
      float pm = -1e30f;
#pragma unroll
      for (int t = 0; t < 4; ++t)
#pragma unroll
        for (int r = 0; r < 4; ++r) {
          float sv = s[q2][t][r] * 0.125f;      // 1/sqrt(64)
          const int key = k0 + t * 16 + 4 * g + r;
          sv = (key > myq) ? -1e30f : sv;       // causal mask
          p[t * 4 + r] = sv;
          pm = fmaxf(pm, sv);
        }
      pm = fmaxf(pm, __shfl_xor(pm, 16));
      pm = fmaxf(pm, __shfl_xor(pm, 32));
      const float mnew = fmaxf(m[q2], pm);
      alpha[q2] = exp2f((m[q2] - mnew) * 1.44269504f);
      float ps = 0.f;
#pragma unroll
      for (int i = 0; i < 16; ++i) {
        p[i] = exp2f((p[i] - mnew) * 1.44269504f);
        ps += p[i];
      }
      ps += __shfl_xor(ps, 16);
      ps += __shfl_xor(ps, 32);
      lsum[q2] = lsum[q2] * alpha[q2] + ps;
      m[q2] = mnew;
#pragma unroll
      for (int t = 0; t < 4; ++t) {
        pf[q2][t][0] = (short)f2b(p[t * 4 + 0]);
        pf[q2][t][1] = (short)f2b(p[t * 4 + 1]);
        pf[q2][t][2] = (short)f2b(p[t * 4 + 2]);
        pf[q2][t][3] = (short)f2b(p[t * 4 + 3]);
      }
    }

    float ar[2][4];
#pragma unroll
    for (int q2 = 0; q2 < 2; ++q2)
#pragma unroll
      for (int r = 0; r < 4; ++r) ar[q2][r] = __shfl(alpha[q2], 4 * g + r);

#pragma unroll
    for (int dt = 0; dt < 4; ++dt) {
#pragma unroll
      for (int q2 = 0; q2 < 2; ++q2) {
        o[q2][dt][0] *= ar[q2][0];
        o[q2][dt][1] *= ar[q2][1];
        o[q2][dt][2] *= ar[q2][2];
        o[q2][dt][3] *= ar[q2][3];
      }
#pragma unroll
      for (int t = 0; t < 4; ++t) {
        o[0][dt] = mfma16(pf[0][t], vf[dt][t], o[0][dt]);
        o[1][dt] = mfma16(pf[1][t], vf[dt][t], o[1][dt]);
      }
    }

#pragma unroll
    for (int t = 0; t < 4; ++t) {
      kcur[t][0] = knxt[t][0];
      kcur[t][1] = knxt[t][1];
    }
  }

#pragma unroll
  for (int q2 = 0; q2 < 2; ++q2) {
    float linv[4];
#pragma unroll
    for (int r = 0; r < 4; ++r) linv[r] = 1.0f / __shfl(lsum[q2], 4 * g + r);
#pragma unroll
    for (int dt = 0; dt < 4; ++dt)
#pragma unroll
      for (int r = 0; r < 4; ++r) {
        const long row = (long)(b * LL + qbase + q2 * 16 + 4 * g + r);
        out[row * HH + h * HDIM + dt * 16 + qi] = o[q2][dt][r] * linv[r] + vbe[dt];
      }
  }
}

extern "C" void kernel_launch(void* const* d_in, const int* in_sizes, int n_in,
                              void* d_out, int out_size, void* d_ws, size_t ws_size,
                              hipStream_t stream) {
  const float* queries = (const float*)d_in[0];
  const float* keys    = (const float*)d_in[1];
  const float* nbr     = (const float*)d_in[2];
  const float* nat     = (const float*)d_in[3];
  const float* pk      = (const float*)d_in[4];
  const float* pv      = (const float*)d_in[5];
  const float* Qw      = (const float*)d_in[6];
  const float* Qbias   = (const float*)d_in[7];
  const float* Kw      = (const float*)d_in[8];
  // const float* Kbias = (const float*)d_in[9];  // softmax-invariant: dropped
  const float* Vw      = (const float*)d_in[10];
  const float* Vbias   = (const float*)d_in[11];  // added in attn epilogue
  // d_in[12] = attn_mask: exact causal ~tril, computed analytically in-kernel.

  unsigned short* Qo = (unsigned short*)d_ws;
  unsigned short* Ko = Qo + (size_t)NROWS * HH;
  unsigned short* Vt = Ko + (size_t)NROWS * HH;
  unsigned short* Wb = Vt + (size_t)NROWS * HH;  // [3][128][128] bf16, linear

  wcvt_kernel<<<48, 256, 0, stream>>>(Qw, Kw, Vw, Wb);

  kv_proj_kernel<<<NROWS / 64, 512, 0, stream>>>(keys, nbr, nat, pk, pv, Wb,
                                                 Ko, Vt);
  q_proj_kernel<<<NROWS / 128, 512, 0, stream>>>(queries, Wb, Qbias, Qo);

  attn_kernel<<<4096, 64, 0, stream>>>(Qo, Ko, Vt, Vbias, (float*)d_out);
}

// Round 14
// 85.759 us; speedup vs baseline: 1.9882x; 1.4130x over previous
//
#include <hip/hip_runtime.h>

typedef __attribute__((ext_vector_type(8))) short bf16x8;
typedef __attribute__((ext_vector_type(4))) short bf16x4;
typedef __attribute__((ext_vector_type(4))) float f32x4;

#define NB 128
#define LL 512
#define HH 128
#define HDIM 64
#define NROWS (NB * LL)  // 65536

__device__ __forceinline__ unsigned short f2b(float f) {
  unsigned int x = __float_as_uint(f);
  x = (x + 0x7fffu + ((x >> 16) & 1u)) >> 16;  // RNE
  return (unsigned short)x;
}

__device__ __forceinline__ bf16x8 load8_cvt(const float* p) {
  float4 a = *(const float4*)p;
  float4 b = *(const float4*)(p + 4);
  bf16x8 r;
  r[0] = (short)f2b(a.x); r[1] = (short)f2b(a.y);
  r[2] = (short)f2b(a.z); r[3] = (short)f2b(a.w);
  r[4] = (short)f2b(b.x); r[5] = (short)f2b(b.y);
  r[6] = (short)f2b(b.z); r[7] = (short)f2b(b.w);
  return r;
}

#if __has_builtin(__builtin_amdgcn_mfma_f32_16x16x16bf16_1k)
__device__ __forceinline__ f32x4 mfma16(bf16x4 a, bf16x4 b, f32x4 c) {
  return __builtin_amdgcn_mfma_f32_16x16x16bf16_1k(a, b, c, 0, 0, 0);
}
#else
__device__ __forceinline__ f32x4 mfma16(bf16x4 a, bf16x4 b, f32x4 c) {
  asm volatile("s_nop 1\n\t"
               "v_mfma_f32_16x16x16_bf16 %0, %1, %2, %0\n\t"
               "s_nop 7\n\t"
               "s_nop 7"
               : "+v"(c) : "v"(a), "v"(b));
  return c;
}
#endif

__device__ __forceinline__ f32x4 mfma32(bf16x8 a, bf16x8 b, f32x4 c) {
  return __builtin_amdgcn_mfma_f32_16x16x32_bf16(a, b, c, 0, 0, 0);
}

// ---------------------------------------------------------------------------
// Weight pre-convert: fp32 -> bf16, LINEAR layout Wb[3][128][128] (Q,K,V).
// ---------------------------------------------------------------------------
__global__ __launch_bounds__(256) void wcvt_kernel(
    const float* __restrict__ Qw, const float* __restrict__ Kw,
    const float* __restrict__ Vw, unsigned short* __restrict__ Wb) {
  const int i = blockIdx.x * 256 + threadIdx.x;  // 0..12287 float4s
  const float* src = (i < 4096) ? Qw : (i < 8192) ? Kw : Vw;
  const int off = (i & 4095) << 2;
  float4 v = *(const float4*)(src + off);
  ushort4 u;
  u.x = f2b(v.x); u.y = f2b(v.y); u.z = f2b(v.z); u.w = f2b(v.w);
  *(ushort4*)(Wb + ((size_t)i << 2)) = u;
}

// ---------------------------------------------------------------------------
// Fused kernel: one block per (b,h). 512 thr = 8 waves. LDS 128KB.
// Phase 1: stage Kw+Vw; project K' (+nbr+nat+pk) -> K_lds (bf16, swizzled),
//          V' (+nbr+nat+pv) -> Vt global. (Kbias dropped: softmax-invariant.)
// Phase 1.5: stage Qw over the Kw region.
// Phase 2: wave w handles paired 32-q chunks (15-w, w) = 9 K-tiles uniform.
//          Q projected on the fly (+Qbias), bounced via wave-private LDS
//          slot into the B-fragment layout; flash attention with K from LDS,
//          V from Vt (L2-hot); +Vbias in epilogue.
// ---------------------------------------------------------------------------
__global__ __launch_bounds__(512) void fused_kernel(
    const float* __restrict__ queries, const float* __restrict__ keys,
    const float* __restrict__ nbr, const float* __restrict__ nat,
    const float* __restrict__ pk, const float* __restrict__ pv,
    const unsigned short* __restrict__ Wb, const float* __restrict__ Qbias,
    const float* __restrict__ Vbias, unsigned short* __restrict__ Vt,
    float* __restrict__ out) {
  __shared__ unsigned short wlds[2 * 128 * 128];  // 64KB: [Kw->Qw | Vw->Qbounce]
  __shared__ unsigned short klds[512 * 64];       // 64KB: K' (swizzled rows)

  const int id = blockIdx.x;   // 0..255
  const int h = id >> 7;       // head
  const int b = id & 127;      // batch; (b,h=0/1) ids differ by 128 = same XCD
  const int tid = threadIdx.x;
  const int lane = tid & 63;
  const int w = tid >> 6;      // wave 0..7
  const int g = lane >> 4;
  const int qi = lane & 15;
  const int rswz = (qi & 7) << 4;

  // ---- stage Kw,Vw (swizzle byte ^= ((row&7)<<4)) ----
#pragma unroll
  for (int i = 0; i < 8; ++i) {
    const int byte = (tid + i * 512) * 16;  // [0, 65536)
    const int row = (byte >> 8) & 127;
    *(bf16x8*)((char*)wlds + (byte ^ ((row & 7) << 4))) =
        *(const bf16x8*)((const char*)Wb + 32768 + byte);
  }
  __syncthreads();

  // ================= Phase 1: K,V projections for rows w*64..w*64+63 =======
  for (int rg = 0; rg < 4; ++rg) {
    const int l = w * 64 + rg * 16 + qi;      // seq position 0..511
    const long roff = ((long)b * LL + l) * 128;

    bf16x8 xk[4];
#pragma unroll
    for (int kt = 0; kt < 4; ++kt)
      xk[kt] = load8_cvt(keys + roff + kt * 32 + g * 8);

    // K projection (Kw at LDS offset 0)
    f32x4 accK[4];
#pragma unroll
    for (int ct = 0; ct < 4; ++ct) {
      accK[ct] = f32x4{0.f, 0.f, 0.f, 0.f};
      const int rw = h * 64 + ct * 16 + qi;   // W row = out col
#pragma unroll
      for (int kt = 0; kt < 4; ++kt) {
        const int byte = rw * 256 + ((kt * 64 + g * 16) ^ rswz);
        bf16x8 wf = *(const bf16x8*)((const char*)wlds + byte);
        accK[ct] = mfma32(wf, xk[kt], accK[ct]);
      }
    }

    float4 tmp[4];
#pragma unroll
    for (int ct = 0; ct < 4; ++ct) {
      const int dl = ct * 16 + 4 * g;         // local col 0..63
      const int cg = h * 64 + dl;             // global col
      const float4 nb4 = *(const float4*)(nbr + roff + cg);
      const float4 na4 = *(const float4*)(nat + roff + cg);
      const float4 pk4 = *(const float4*)(pk + roff + cg);
      float4 t;
      t.x = nb4.x + na4.x; t.y = nb4.y + na4.y;
      t.z = nb4.z + na4.z; t.w = nb4.w + na4.w;
      tmp[ct] = t;
      ushort4 u;
      u.x = f2b(accK[ct][0] + t.x + pk4.x);
      u.y = f2b(accK[ct][1] + t.y + pk4.y);
      u.z = f2b(accK[ct][2] + t.z + pk4.z);
      u.w = f2b(accK[ct][3] + t.w + pk4.w);
      const int kb = l * 128 + dl * 2;
      *(ushort4*)((char*)klds + (kb ^ ((l & 7) << 4))) = u;
    }

    // V projection (Vw at LDS offset 32768)
    f32x4 accV[4];
#pragma unroll
    for (int ct = 0; ct < 4; ++ct) {
      accV[ct] = f32x4{0.f, 0.f, 0.f, 0.f};
      const int rw = h * 64 + ct * 16 + qi;
#pragma unroll
      for (int kt = 0; kt < 4; ++kt) {
        const int byte = 32768 + rw * 256 + ((kt * 64 + g * 16) ^ rswz);
        bf16x8 wf = *(const bf16x8*)((const char*)wlds + byte);
        accV[ct] = mfma32(wf, xk[kt], accV[ct]);
      }
    }
#pragma unroll
    for (int ct = 0; ct < 4; ++ct) {
      const int dl = ct * 16 + 4 * g;
      const int cg = h * 64 + dl;
      const float4 pv4 = *(const float4*)(pv + roff + cg);
      unsigned short* vp = Vt + (((long)h * NB + b) * HDIM + dl) * LL + l;
      vp[0 * LL] = f2b(accV[ct][0] + tmp[ct].x + pv4.x);
      vp[1 * LL] = f2b(accV[ct][1] + tmp[ct].y + pv4.y);
      vp[2 * LL] = f2b(accV[ct][2] + tmp[ct].z + pv4.z);
      vp[3 * LL] = f2b(accV[ct][3] + tmp[ct].w + pv4.w);
    }
  }

  __syncthreads();  // all waves done with Kw/Vw; K_lds complete; Vt drained

  // ---- stage Qw over the Kw region ----
#pragma unroll
  for (int i = 0; i < 4; ++i) {
    const int byte = (tid + i * 512) * 16;  // [0, 32768)
    const int row = (byte >> 8) & 127;
    *(bf16x8*)((char*)wlds + (byte ^ ((row & 7) << 4))) =
        *(const bf16x8*)((const char*)Wb + byte);
  }
  __syncthreads();

  // ================= Phase 2: Q-proj + flash attention =====================
  float vbe[4];
#pragma unroll
  for (int dt = 0; dt < 4; ++dt) vbe[dt] = Vbias[h * 64 + dt * 16 + qi];

  char* slot = (char*)wlds + 32768 + w * 2048;  // wave-private Q bounce
  const unsigned short* Vbase = Vt + ((long)h * NB + b) * HDIM * LL;

  for (int half = 0; half < 2; ++half) {
    const int c = half ? w : 15 - w;  // paired chunks: 9 tiles total, uniform
    const int qbase = c * 32;
    const int ntile = (c >> 1) + 1;

    // --- Q projection for 32 rows, bounced to B-fragment layout ---
    bf16x8 qf[2][2];
#pragma unroll
    for (int q2 = 0; q2 < 2; ++q2) {
      const int l = qbase + q2 * 16 + qi;
      const long roff = ((long)b * LL + l) * 128;
      bf16x8 xq[4];
#pragma unroll
      for (int kt = 0; kt < 4; ++kt)
        xq[kt] = load8_cvt(queries + roff + kt * 32 + g * 8);
      f32x4 aq[4];
#pragma unroll
      for (int ct = 0; ct < 4; ++ct) {
        aq[ct] = f32x4{0.f, 0.f, 0.f, 0.f};
        const int rw = h * 64 + ct * 16 + qi;
#pragma unroll
        for (int kt = 0; kt < 4; ++kt) {
          const int byte = rw * 256 + ((kt * 64 + g * 16) ^ rswz);
          bf16x8 wf = *(const bf16x8*)((const char*)wlds + byte);
          aq[ct] = mfma32(wf, xq[kt], aq[ct]);
        }
      }
#pragma unroll
      for (int ct = 0; ct < 4; ++ct) {
        const int dl = ct * 16 + 4 * g;
        const float4 bv = *(const float4*)(Qbias + h * 64 + dl);
        ushort4 u;
        u.x = f2b(aq[ct][0] + bv.x);
        u.y = f2b(aq[ct][1] + bv.y);
        u.z = f2b(aq[ct][2] + bv.z);
        u.w = f2b(aq[ct][3] + bv.w);
        const int bb = qi * 128 + dl * 2;
        *(ushort4*)(slot + (bb ^ ((qi & 7) << 4))) = u;
      }
      asm volatile("s_waitcnt lgkmcnt(0)" ::: "memory");
      __builtin_amdgcn_sched_barrier(0);
      qf[q2][0] = *(const bf16x8*)(slot + ((qi * 128 + g * 16) ^ ((qi & 7) << 4)));
      qf[q2][1] = *(const bf16x8*)(slot + ((qi * 128 + 64 + g * 16) ^ ((qi & 7) << 4)));
    }

    // --- flash attention over K_lds / Vt ---
    f32x4 o[2][4];
#pragma unroll
    for (int q2 = 0; q2 < 2; ++q2)
#pragma unroll
      for (int dt = 0; dt < 4; ++dt) o[q2][dt] = f32x4{0.f, 0.f, 0.f, 0.f};
    float m[2] = {-1e30f, -1e30f};
    float lsum[2] = {0.f, 0.f};

    for (int it = 0; it < ntile; ++it) {
      const int k0 = it * 64;

      bf16x8 kf[4][2];
#pragma unroll
      for (int t = 0; t < 4; ++t) {
        const int l = k0 + t * 16 + qi;
        const int base = l * 128;
        const int sz = (l & 7) << 4;
        kf[t][0] = *(const bf16x8*)((char*)klds + ((base + g * 16) ^ sz));
        kf[t][1] = *(const bf16x8*)((char*)klds + ((base + 64 + g * 16) ^ sz));
      }

      bf16x4 vf[4][4];
#pragma unroll
      for (int dt = 0; dt < 4; ++dt)
#pragma unroll
        for (int t = 0; t < 4; ++t)
          vf[dt][t] = *(const bf16x4*)(Vbase + (dt * 16 + qi) * LL + k0 +
                                       t * 16 + 4 * g);

      f32x4 s[2][4];
#pragma unroll
      for (int q2 = 0; q2 < 2; ++q2)
#pragma unroll
        for (int t = 0; t < 4; ++t) {
          f32x4 acc = f32x4{0.f, 0.f, 0.f, 0.f};
          acc = mfma32(kf[t][0], qf[q2][0], acc);
          acc = mfma32(kf[t][1], qf[q2][1], acc);
          s[q2][t] = acc;
        }

      float alpha[2];
      bf16x4 pf[2][4];
#pragma unroll
      for (int q2 = 0; q2 < 2; ++q2) {
        const int myq = qbase + q2 * 16 + qi;
        float p[16];
        float pm = -1e30f;
#pragma unroll
        for (int t = 0; t < 4; ++t)
#pragma unroll
          for (int r = 0; r < 4; ++r) {
            float sv = s[q2][t][r] * 0.125f;    // 1/sqrt(64)
            const int key = k0 + t * 16 + 4 * g + r;
            sv = (key > myq) ? -1e30f : sv;     // causal mask
            p[t * 4 + r] = sv;
            pm = fmaxf(pm, sv);
          }
        pm = fmaxf(pm, __shfl_xor(pm, 16));
        pm = fmaxf(pm, __shfl_xor(pm, 32));
        const float mnew = fmaxf(m[q2], pm);
        alpha[q2] = exp2f((m[q2] - mnew) * 1.44269504f);
        float ps = 0.f;
#pragma unroll
        for (int i = 0; i < 16; ++i) {
          p[i] = exp2f((p[i] - mnew) * 1.44269504f);
          ps += p[i];
        }
        ps += __shfl_xor(ps, 16);
        ps += __shfl_xor(ps, 32);
        lsum[q2] = lsum[q2] * alpha[q2] + ps;
        m[q2] = mnew;
#pragma unroll
        for (int t = 0; t < 4; ++t) {
          pf[q2][t][0] = (short)f2b(p[t * 4 + 0]);
          pf[q2][t][1] = (short)f2b(p[t * 4 + 1]);
          pf[q2][t][2] = (short)f2b(p[t * 4 + 2]);
          pf[q2][t][3] = (short)f2b(p[t * 4 + 3]);
        }
      }

      float ar[2][4];
#pragma unroll
      for (int q2 = 0; q2 < 2; ++q2)
#pragma unroll
        for (int r = 0; r < 4; ++r) ar[q2][r] = __shfl(alpha[q2], 4 * g + r);

#pragma unroll
      for (int dt = 0; dt < 4; ++dt) {
#pragma unroll
        for (int q2 = 0; q2 < 2; ++q2) {
          o[q2][dt][0] *= ar[q2][0];
          o[q2][dt][1] *= ar[q2][1];
          o[q2][dt][2] *= ar[q2][2];
          o[q2][dt][3] *= ar[q2][3];
        }
#pragma unroll
        for (int t = 0; t < 4; ++t) {
          o[0][dt] = mfma16(pf[0][t], vf[dt][t], o[0][dt]);
          o[1][dt] = mfma16(pf[1][t], vf[dt][t], o[1][dt]);
        }
      }
    }

    // epilogue (+Vbias, exact since softmax weights sum to 1)
#pragma unroll
    for (int q2 = 0; q2 < 2; ++q2) {
      float linv[4];
#pragma unroll
      for (int r = 0; r < 4; ++r) linv[r] = 1.0f / __shfl(lsum[q2], 4 * g + r);
#pragma unroll
      for (int dt = 0; dt < 4; ++dt)
#pragma unroll
        for (int r = 0; r < 4; ++r) {
          const long row = (long)b * LL + qbase + q2 * 16 + 4 * g + r;
          out[row * HH + h * 64 + dt * 16 + qi] =
              o[q2][dt][r] * linv[r] + vbe[dt];
        }
    }
  }
}

extern "C" void kernel_launch(void* const* d_in, const int* in_sizes, int n_in,
                              void* d_out, int out_size, void* d_ws, size_t ws_size,
                              hipStream_t stream) {
  const float* queries = (const float*)d_in[0];
  const float* keys    = (const float*)d_in[1];
  const float* nbr     = (const float*)d_in[2];
  const float* nat     = (const float*)d_in[3];
  const float* pk      = (const float*)d_in[4];
  const float* pv      = (const float*)d_in[5];
  const float* Qw      = (const float*)d_in[6];
  const float* Qbias   = (const float*)d_in[7];
  const float* Kw      = (const float*)d_in[8];
  // const float* Kbias = (const float*)d_in[9];  // softmax-invariant: dropped
  const float* Vw      = (const float*)d_in[10];
  const float* Vbias   = (const float*)d_in[11];  // added in attn epilogue
  // d_in[12] = attn_mask: exact causal ~tril, computed analytically in-kernel.

  unsigned short* Vt = (unsigned short*)d_ws;          // [2][128][64][512] bf16
  unsigned short* Wb = Vt + (size_t)2 * NB * HDIM * LL;  // [3][128][128] bf16

  wcvt_kernel<<<48, 256, 0, stream>>>(Qw, Kw, Vw, Wb);

  fused_kernel<<<256, 512, 0, stream>>>(queries, keys, nbr, nat, pk, pv, Wb,
                                        Qbias, Vbias, Vt, (float*)d_out);
}